// Round 3
// baseline (807.575 us; speedup 1.0000x reference)
//
#include <hip/hip_runtime.h>

typedef unsigned short u16;
typedef unsigned int   u32;
typedef unsigned long long u64;
typedef __bf16 bf16x8 __attribute__((ext_vector_type(8)));
typedef float  floatx4 __attribute__((ext_vector_type(4)));

#define DEV static __device__ __forceinline__

DEV u16 f2bf(float f){ u32 x = __float_as_uint(f); return (u16)((x + 0x7fffu + ((x>>16)&1u)) >> 16); }
DEV float bf2f(u16 h){ return __uint_as_float(((u32)h)<<16); }

DEV void load_lds16(const u16* g, u16* l){
  __builtin_amdgcn_global_load_lds((const __attribute__((address_space(1))) u32*)g,
                                   (__attribute__((address_space(3))) u32*)l, 16, 0, 0);
}

// ---------------------------------------------------------------------------
// Generic NT GEMM: C[m,n] = sum_k A[m,k]*B[n,k]  (A,B bf16 row-major, C fp32)
// BM=128, BK=32, 256 threads (4 waves as 2x2), 16x16x32 bf16 MFMA.
// MODE 0: C fp32 (+optional bias[n]), stores guarded by col<ncmax.
// MODE 1 (BN=64): AV epilogue — res[z][i][d] (+)= alpha*C (alpha=sigmoid),
//   and vout[z][d][i] = bf16(C) (transposed) for the next order.
// ---------------------------------------------------------------------------
template<int BN, int MODE>
__global__ __launch_bounds__(256) void gemm_bt(
    const u16* __restrict__ A, const u16* __restrict__ Bm, float* __restrict__ C,
    const float* __restrict__ bias, int K, int lda, int ldb, int ldc, int ncmax,
    long long sA, long long sB, long long sC,
    u16* __restrict__ vout, float* __restrict__ resb, const float* __restrict__ araw,
    int order, int accum)
{
  constexpr int BM = 128, BK = 32;
  constexpr int NT = (BN/2)/16;           // 4 for BN=128, 2 for BN=64
  __shared__ u16 smem[8704];              // staging (<=8192 u16) / 64x136 transpose
  u16* As = smem;                         // BM*BK = 4096 u16
  u16* Bs = smem + 4096;                  // BN*BK

  const int tid = threadIdx.x, wid = tid>>6, lane = tid&63;
  const int z = blockIdx.z;
  const int m0 = blockIdx.y * BM, n0 = blockIdx.x * BN;
  const u16* Ab = A + (long long)z*sA;
  const u16* Bb = Bm + (long long)z*sB;

  const int srow = tid>>2, schunk = (tid&3)*8;
  const u16* ga0 = Ab + (long long)(m0 + srow)*lda + schunk;
  const u16* ga1 = Ab + (long long)(m0 + 64 + srow)*lda + schunk;
  const u16* gb0 = Bb + (long long)(n0 + srow)*ldb + schunk;
  const u16* gb1 = Bb + (long long)(n0 + 64 + srow)*ldb + schunk;  // BN==128 only

  u16* lA0 = As + (wid*16)*BK;
  u16* lA1 = As + (64 + wid*16)*BK;
  u16* lB0 = Bs + (wid*16)*BK;
  u16* lB1 = Bs + (64 + wid*16)*BK;

  const int wm = wid>>1, wn = wid&1;
  const int lr = lane&15, lk = (lane>>4)*8, lq = lane>>4;

  floatx4 acc[4][NT] = {};

  for (int k = 0; k < K; k += BK) {
    __syncthreads();
    load_lds16(ga0 + k, lA0);
    load_lds16(ga1 + k, lA1);
    load_lds16(gb0 + k, lB0);
    if (BN == 128) load_lds16(gb1 + k, lB1);
    __syncthreads();
    bf16x8 af[4];
#pragma unroll
    for (int mt=0; mt<4; ++mt)
      af[mt] = *(const bf16x8*)(As + (wm*64 + mt*16 + lr)*BK + lk);
#pragma unroll
    for (int nt=0; nt<NT; ++nt) {
      bf16x8 bfr = *(const bf16x8*)(Bs + (wn*(BN/2) + nt*16 + lr)*BK + lk);
#pragma unroll
      for (int mt=0; mt<4; ++mt)
        acc[mt][nt] = __builtin_amdgcn_mfma_f32_16x16x32_bf16(af[mt], bfr, acc[mt][nt], 0, 0, 0);
    }
  }

  if constexpr (MODE == 0) {
    float* Cb = C + (long long)z*sC;
#pragma unroll
    for (int nt=0; nt<NT; ++nt) {
      const int col = n0 + wn*(BN/2) + nt*16 + lr;
      if (col < ncmax) {
        const float bv = bias ? bias[col] : 0.f;
#pragma unroll
        for (int mt=0; mt<4; ++mt) {
#pragma unroll
          for (int r=0; r<4; ++r) {
            const int row = m0 + wm*64 + mt*16 + lq*4 + r;
            Cb[(long long)row*ldc + col] = acc[mt][nt][r] + bv;
          }
        }
      }
    }
  } else {
    const int h = z & 15;
    const float alpha = 1.f/(1.f + __expf(-araw[order*16 + h]));
    float* rb = resb + (long long)z * 65536;   // res[z][1024][64]
    __syncthreads();                           // staging LDS reuse as transpose buf
#pragma unroll
    for (int nt=0; nt<NT; ++nt) {
      const int d = wn*32 + nt*16 + lr;
#pragma unroll
      for (int mt=0; mt<4; ++mt) {
#pragma unroll
        for (int r=0; r<4; ++r) {
          const int row = wm*64 + mt*16 + lq*4 + r;
          const float v = acc[mt][nt][r];
          const long long ri = (long long)(m0+row)*64 + d;
          rb[ri] = accum ? (rb[ri] + alpha*v) : (alpha*v);
          smem[d*136 + row] = f2bf(v);
        }
      }
    }
    __syncthreads();
    const int dd = tid>>2, cc = (tid&3)*32;
    u16* vp = vout + (long long)z*75776 + (long long)dd*1184 + m0 + cc;  // vout[z][64][1184]
    const u16* sp = smem + dd*136 + cc;
#pragma unroll
    for (int j=0; j<32; j+=8) {
      uint4 uu;
      uu.x = sp[j+0] | ((u32)sp[j+1]<<16);
      uu.y = sp[j+2] | ((u32)sp[j+3]<<16);
      uu.z = sp[j+4] | ((u32)sp[j+5]<<16);
      uu.w = sp[j+6] | ((u32)sp[j+7]<<16);
      *(uint4*)(vp + j) = uu;
    }
  }
}

// ---------------------------------------------------------------------------
// Elementwise prep kernels
// ---------------------------------------------------------------------------
// fp32 [rows,1024] -> bf16 [rows,3072]; A-mode (hi|lo|hi), B-mode (hi|hi|lo)
__global__ __launch_bounds__(256) void planeize(const float* __restrict__ src, u16* __restrict__ dst,
                                                int total, int modeB){
  int idx = blockIdx.x*256 + threadIdx.x;
  if (idx >= total) return;
  int c = idx & 1023, r = idx >> 10;
  float v = src[idx];
  u16 hi = f2bf(v); u16 lo = f2bf(v - bf2f(hi));
  u16* d = dst + (long long)r*3072 + c;
  if (modeB){ d[0]=hi; d[1024]=hi; d[2048]=lo; }
  else      { d[0]=hi; d[1024]=lo; d[2048]=hi; }
}

// qkv fp32 [4096,3072] -> qS [bh,1024,192] (A-mode) and kxS rows 0..1023 (B-mode, k*0.125)
__global__ __launch_bounds__(256) void build_qk(const float* __restrict__ qkv,
                                                u16* __restrict__ qS, u16* __restrict__ kxS){
  int idx = blockIdx.x*256 + threadIdx.x;   // ((b*16+h)*1024+n)*64+d
  int d = idx & 63, n = (idx>>6) & 1023, bh = idx >> 16;
  int b = bh >> 4, h = bh & 15;
  long long src = (long long)(b*1024 + n)*3072 + h*64 + d;
  float qv = qkv[src];
  float kv = qkv[src + 1024] * 0.125f;
  u16 qhi=f2bf(qv), qlo=f2bf(qv - bf2f(qhi));
  u16 khi=f2bf(kv), klo=f2bf(kv - bf2f(khi));
  u16* q  = qS  + ((long long)bh*1024 + n)*192 + d;
  q[0]=qhi; q[64]=qlo; q[128]=qhi;
  u16* kx = kxS + ((long long)bh*1280 + n)*192 + d;
  kx[0]=khi; kx[64]=khi; kx[128]=klo;
}

// kxS rows 1024..1279: rel_k_emb planes (B-mode), zero pad rows
__global__ __launch_bounds__(256) void build_kxrel(const float* __restrict__ relk, u16* __restrict__ kxS){
  int idx = blockIdx.x*256 + threadIdx.x;   // (bh, t:256, d:64)
  int d = idx & 63, t = (idx>>6) & 255, bh = idx >> 14;
  u16 hi=0, lo=0;
  if (t < 129){ float v = relk[t*64 + d]; hi = f2bf(v); lo = f2bf(v - bf2f(hi)); }
  u16* kx = kxS + ((long long)bh*1280 + 1024 + t)*192 + d;
  kx[0]=hi; kx[64]=hi; kx[128]=lo;
}

// v part of qkv -> vA[bh][d][n] (transposed, bf16) via LDS tiles
__global__ __launch_bounds__(256) void build_vT(const float* __restrict__ qkv, u16* __restrict__ vA){
  __shared__ float tb[64][65];
  int bh = blockIdx.x >> 4, ntile = blockIdx.x & 15;
  int b = bh >> 4, h = bh & 15;
  int tid = threadIdx.x;
  int nl = tid >> 2, dc = (tid & 3)*16;
  const float* sp = qkv + (long long)(b*1024 + ntile*64 + nl)*3072 + 2048 + h*64 + dc;
#pragma unroll
  for (int j=0;j<16;j+=4){
    float4 f = *(const float4*)(sp + j);
    tb[dc+j+0][nl]=f.x; tb[dc+j+1][nl]=f.y; tb[dc+j+2][nl]=f.z; tb[dc+j+3][nl]=f.w;
  }
  __syncthreads();
  int d = tid >> 2, nc = (tid & 3)*16;
  u16* dp = vA + ((long long)bh*64 + d)*1184 + ntile*64 + nc;
#pragma unroll
  for (int j=0;j<16;j+=8){
    u16 a0=f2bf(tb[d][nc+j+0]), a1=f2bf(tb[d][nc+j+1]), a2=f2bf(tb[d][nc+j+2]), a3=f2bf(tb[d][nc+j+3]);
    u16 a4=f2bf(tb[d][nc+j+4]), a5=f2bf(tb[d][nc+j+5]), a6=f2bf(tb[d][nc+j+6]), a7=f2bf(tb[d][nc+j+7]);
    uint4 uu; uu.x=a0|((u32)a1<<16); uu.y=a2|((u32)a3<<16); uu.z=a4|((u32)a5<<16); uu.w=a6|((u32)a7<<16);
    *(uint4*)(dp + j) = uu;
  }
}

// vA ext cols: [bh][d][1024+t] = rel_v_emb[t][d] (t<129), 0 for t 129..159
__global__ __launch_bounds__(256) void build_vText(const float* __restrict__ relv, u16* __restrict__ vA){
  int idx = blockIdx.x*256 + threadIdx.x;   // (bh, d, t:160)
  int t = idx % 160; int rest = idx / 160; int d = rest & 63; int bh = rest >> 6;
  u16 hv = 0;
  if (t < 129) hv = f2bf(relv[t*64 + d]);
  vA[((long long)bh*64 + d)*1184 + 1024 + t] = hv;
}

// res [bh][n][d] fp32 -> resS [b*1024+n][3072] A-mode planes at col h*64+d
__global__ __launch_bounds__(256) void build_resS(const float* __restrict__ res, u16* __restrict__ resS){
  int idx = blockIdx.x*256 + threadIdx.x;
  int d = idx & 63, n = (idx>>6) & 1023, bh = idx >> 16;
  int b = bh >> 4, h = bh & 15;
  float v = res[idx];
  u16 hi = f2bf(v), lo = f2bf(v - bf2f(hi));
  u16* p = resS + (long long)(b*1024 + n)*3072 + h*64 + d;
  p[0]=hi; p[1024]=lo; p[2048]=hi;
}

// ---------------------------------------------------------------------------
// Per-row (one wave per row): scores row (ld 1156: cols 0..1023 = QK^T+band
// via GEMM-folded rel cols 1024..1152), exact 256th-largest threshold (radix
// bisection on sortable-uint), masked softmax. Writes P (bf16, 1184 cols:
// 1024 probs + 129 rel_v bucket weights + 31 zeros) IN PLACE over the S row.
// Safe: each wave reads only its own row fully before writing it.
// ---------------------------------------------------------------------------
__global__ __launch_bounds__(256) void topk_softmax(float* S){
  __shared__ float rel[4][132];
  __shared__ float prow[4][1024];
  const int tid = threadIdx.x, wid = tid>>6, lane = tid&63;
  const int rowid = blockIdx.x*4 + wid;     // 0..32767 (one half-batch)
  const int i = rowid & 1023;
  float* Sr = S + (long long)rowid * 1156;

  rel[wid][lane]      = Sr[1024 + lane];    // rel idx 0..63
  rel[wid][64 + lane] = Sr[1088 + lane];    // rel idx 64..127
  if (lane == 0) rel[wid][128] = Sr[1152];  // rel idx 128 (t=128 bucket) — R2 bugfix

  float v[16];
#pragma unroll
  for (int r=0;r<4;++r){
    float4 f = *(const float4*)(Sr + r*256 + lane*4);
    v[r*4+0]=f.x; v[r*4+1]=f.y; v[r*4+2]=f.z; v[r*4+3]=f.w;
  }
  __syncthreads();   // all S reads complete before any in-place P write below
#pragma unroll
  for (int x=0;x<16;++x){
    const int j = (x>>2)*256 + lane*4 + (x&3);
    int dl = i - j; dl = dl > 64 ? 64 : (dl < -64 ? -64 : dl);
    v[x] += rel[wid][dl + 64];
  }
  u32 u[16];
#pragma unroll
  for (int x=0;x<16;++x){
    u32 bb = __float_as_uint(v[x]);
    u[x] = bb ^ ((u32)((int)bb >> 31) | 0x80000000u);
  }
  u32 thr = 0;
  for (int bit=31; bit>=0; --bit){
    const u32 cand = thr | (1u<<bit);
    int c = 0;
#pragma unroll
    for (int x=0;x<16;++x) c += __popcll(__ballot(u[x] >= cand));
    if (c >= 256) thr = cand;
  }
  float m = -3.0e38f;
#pragma unroll
  for (int x=0;x<16;++x) m = fmaxf(m, v[x]);
  for (int o=32;o;o>>=1) m = fmaxf(m, __shfl_xor(m, o));
  float e[16]; float Z = 0.f;
#pragma unroll
  for (int x=0;x<16;++x){
    e[x] = (u[x] >= thr) ? __expf(v[x]-m) : 0.f;
    Z += e[x];
  }
  for (int o=32;o;o>>=1) Z += __shfl_xor(Z, o);
  const float rz = 1.f / Z;

  u16* Pr = (u16*)Sr;                       // in-place: P row stride 2312 u16
#pragma unroll
  for (int r=0;r<4;++r){
    float p0=e[r*4+0]*rz, p1=e[r*4+1]*rz, p2=e[r*4+2]*rz, p3=e[r*4+3]*rz;
    prow[wid][r*256+lane*4+0]=p0; prow[wid][r*256+lane*4+1]=p1;
    prow[wid][r*256+lane*4+2]=p2; prow[wid][r*256+lane*4+3]=p3;
    uint2 uu; uu.x = f2bf(p0) | ((u32)f2bf(p1)<<16); uu.y = f2bf(p2) | ((u32)f2bf(p3)<<16);
    *(uint2*)(Pr + r*256 + lane*4) = uu;
  }
  float s0 = 0.f, s1 = 0.f;
#pragma unroll
  for (int x=0;x<16;++x){
    const int j = (x>>2)*256 + lane*4 + (x&3);
    const float p = e[x]*rz;
    if (j >= i+64) s0 += p;    // dist bucket t=0   (j >= i+64)
    if (j <= i-64) s1 += p;    // dist bucket t=128 (j <= i-64)
  }
  for (int o=32;o;o>>=1){ s0 += __shfl_xor(s0,o); s1 += __shfl_xor(s1,o); }
  {
    const int t = lane + 1;                 // 1..64
    const int j = i + 64 - t;
    const float wv = (j>=0 && j<1024) ? prow[wid][j] : 0.f;
    Pr[1024 + t] = f2bf(wv);
    if (lane < 63){
      const int t2 = lane + 65;             // 65..127
      const int j2 = i + 64 - t2;
      const float wv2 = (j2>=0 && j2<1024) ? prow[wid][j2] : 0.f;
      Pr[1024 + t2] = f2bf(wv2);
    }
    if (lane == 0){ Pr[1024] = f2bf(s0); Pr[1152] = f2bf(s1); }
    if (lane >= 33) Pr[1120 + lane] = 0;    // zero cols 1153..1183
  }
}

// ---------------------------------------------------------------------------
extern "C" void kernel_launch(void* const* d_in, const int* in_sizes, int n_in,
                              void* d_out, int out_size, void* d_ws, size_t ws_size,
                              hipStream_t stream) {
  const float* x    = (const float*)d_in[0];
  const float* Wqkv = (const float*)d_in[1];
  const float* bqkv = (const float*)d_in[2];
  const float* Wout = (const float*)d_in[3];
  const float* bout = (const float*)d_in[4];
  const float* relk = (const float*)d_in[5];
  const float* relv = (const float*)d_in[6];
  const float* araw = (const float*)d_in[7];
  float* out = (float*)d_out;

  char* w = (char*)d_ws;
  size_t off = 0;
  auto take = [&](size_t bytes)->char*{ char* p = w + off; off += (bytes + 255) & ~(size_t)255; return p; };

  // regionS (151.5 MB): phase1 {xS|wqS|qkv32} -> per-half {S/P overlay} -> {resS|woS}
  char* regionS = take(151519232);          // 32*1024 rows * 1156 fp32
  u16*   xS    = (u16*)  (regionS);
  u16*   wqS   = (u16*)  (regionS + 25165824);
  float* qkv32 = (float*)(regionS + 25165824 + 18874368);
  float* Sh    = (float*)(regionS);
  u16*   Ph    = (u16*)  (regionS);         // in-place, row stride 2312 u16
  u16*   resS  = (u16*)  (regionS);
  u16*   woS   = (u16*)  (regionS + 25165824);
  u16*   qS    = (u16*)take(25165824);      // [64][1024][192]
  u16*   kxS   = (u16*)take(31457280);      // [64][1280][192]
  u16*   vA    = (u16*)take(9699328);       // [64][64][1184]
  u16*   vB    = (u16*)take(9699328);
  float* res   = (float*)take(16777216);    // [64][1024][64]
  (void)ws_size; (void)in_sizes; (void)n_in; (void)out_size;
  // total ~233 MiB

  // phase 1: QKV projection (fp32 via split-bf16 K-stacked planes)
  planeize<<<16384,256,0,stream>>>(x,    xS,  4194304, 0);
  planeize<<<12288,256,0,stream>>>(Wqkv, wqS, 3145728, 1);
  gemm_bt<128,0><<<dim3(24,32,1),256,0,stream>>>(xS, wqS, qkv32, bqkv,
      3072, 3072, 3072, 3072, 3072, 0, 0, 0, nullptr, nullptr, nullptr, 0, 0);
  build_qk   <<<16384,256,0,stream>>>(qkv32, qS, kxS);
  build_kxrel<<<4096, 256,0,stream>>>(relk, kxS);
  build_vT   <<<1024, 256,0,stream>>>(qkv32, vA);
  build_vText<<<2560, 256,0,stream>>>(relv, vA);

  // phases 2+3 per 32-head half: scores -> topk/softmax (P in place) -> 3x AV
  for (int half = 0; half < 2; ++half) {
    const long long zo = (long long)half * 32;
    gemm_bt<128,0><<<dim3(10,8,32),256,0,stream>>>(
        qS + zo*196608, kxS + zo*245760, Sh, nullptr,
        192, 192, 192, 1156, 1153, 196608LL, 245760LL, 1183744LL,
        nullptr, nullptr, nullptr, 0, 0);
    topk_softmax<<<8192,256,0,stream>>>(Sh);
    gemm_bt<64,1><<<dim3(1,8,32),256,0,stream>>>(Ph, vA + zo*75776, nullptr, nullptr,
        1184, 2312, 1184, 0, 0, 2367488LL, 75776LL, 0LL,
        vB + zo*75776, res + zo*65536, araw, 0, 0);
    gemm_bt<64,1><<<dim3(1,8,32),256,0,stream>>>(Ph, vB + zo*75776, nullptr, nullptr,
        1024, 2312, 1184, 0, 0, 2367488LL, 75776LL, 0LL,
        vA + zo*75776, res + zo*65536, araw, 1, 1);
    gemm_bt<64,1><<<dim3(1,8,32),256,0,stream>>>(Ph, vA + zo*75776, nullptr, nullptr,
        1024, 2312, 1184, 0, 0, 2367488LL, 75776LL, 0LL,
        vB + zo*75776, res + zo*65536, araw, 2, 1);
  }

  // output projection (fp32 via split planes)
  build_resS<<<16384,256,0,stream>>>(res, resS);
  planeize  <<<4096, 256,0,stream>>>(Wout, woS, 1048576, 1);
  gemm_bt<128,0><<<dim3(8,32,1),256,0,stream>>>(resS, woS, out, bout,
      3072, 3072, 3072, 1024, 1024, 0, 0, 0, nullptr, nullptr, nullptr, 0, 0);
}

// Round 4
// 710.944 us; speedup vs baseline: 1.1359x; 1.1359x over previous
//
#include <hip/hip_runtime.h>

typedef unsigned short u16;
typedef unsigned int   u32;
typedef unsigned long long u64;
typedef __bf16 bf16x8 __attribute__((ext_vector_type(8)));
typedef float  floatx4 __attribute__((ext_vector_type(4)));

#define DEV static __device__ __forceinline__

DEV u16 f2bf(float f){ u32 x = __float_as_uint(f); return (u16)((x + 0x7fffu + ((x>>16)&1u)) >> 16); }
DEV float bf2f(u16 h){ return __uint_as_float(((u32)h)<<16); }

DEV void load_lds16(const u16* g, u16* l){
  __builtin_amdgcn_global_load_lds((const __attribute__((address_space(1))) u32*)g,
                                   (__attribute__((address_space(3))) u32*)l, 16, 0, 0);
}

// ---------------------------------------------------------------------------
// Generic NT GEMM: C[m,n] = sum_k A[m,k]*B[n,k]  (A,B bf16 row-major, C fp32)
// BM in {64,128}, BN in {64,128}, BK=32, 256 threads (4 waves as 2x2).
// MODE 0: C fp32 (+optional bias[n]), stores guarded by col<ncmax.
// MODE 1 (BN=64): AV epilogue — res[z][i][d] (+)= alpha*C (alpha=sigmoid),
//   and vout[z][d][i] = bf16(C) (transposed) for the next order.
// ---------------------------------------------------------------------------
template<int BM, int BN, int MODE>
__global__ __launch_bounds__(256) void gemm_bt(
    const u16* __restrict__ A, const u16* __restrict__ Bm, float* __restrict__ C,
    const float* __restrict__ bias, int K, int lda, int ldb, int ldc, int ncmax,
    long long sA, long long sB, long long sC,
    u16* __restrict__ vout, float* __restrict__ resb, const float* __restrict__ araw,
    int order, int accum)
{
  constexpr int BK = 32;
  constexpr int MT = BM/32;               // m-tiles per wave (wave covers BM/2 rows)
  constexpr int NT = (BN/2)/16;           // n-tiles per wave
  __shared__ u16 smem[8704];              // staging (<=8192 u16) / 64x136 transpose
  u16* As = smem;                         // BM*BK u16
  u16* Bs = smem + BM*BK;                 // BN*BK u16

  const int tid = threadIdx.x, wid = tid>>6, lane = tid&63;
  const int z = blockIdx.z;
  const int m0 = blockIdx.y * BM, n0 = blockIdx.x * BN;
  const u16* Ab = A + (long long)z*sA;
  const u16* Bb = Bm + (long long)z*sB;

  const int srow = tid>>2, schunk = (tid&3)*8;
  const u16* ga0 = Ab + (long long)(m0 + srow)*lda + schunk;
  const u16* gb0 = Bb + (long long)(n0 + srow)*ldb + schunk;
  const u16* ga1 = (BM==128) ? Ab + (long long)(m0 + 64 + srow)*lda + schunk : nullptr;
  const u16* gb1 = (BN==128) ? Bb + (long long)(n0 + 64 + srow)*ldb + schunk : nullptr;

  u16* lA0 = As + (wid*16)*BK;
  u16* lA1 = As + (64 + wid*16)*BK;
  u16* lB0 = Bs + (wid*16)*BK;
  u16* lB1 = Bs + (64 + wid*16)*BK;

  const int wm = wid>>1, wn = wid&1;
  const int lr = lane&15, lk = (lane>>4)*8, lq = lane>>4;

  floatx4 acc[MT][NT] = {};

  for (int k = 0; k < K; k += BK) {
    __syncthreads();
    load_lds16(ga0 + k, lA0);
    if constexpr (BM == 128) load_lds16(ga1 + k, lA1);
    load_lds16(gb0 + k, lB0);
    if constexpr (BN == 128) load_lds16(gb1 + k, lB1);
    __syncthreads();
    bf16x8 af[MT];
#pragma unroll
    for (int mt=0; mt<MT; ++mt)
      af[mt] = *(const bf16x8*)(As + (wm*(BM/2) + mt*16 + lr)*BK + lk);
#pragma unroll
    for (int nt=0; nt<NT; ++nt) {
      bf16x8 bfr = *(const bf16x8*)(Bs + (wn*(BN/2) + nt*16 + lr)*BK + lk);
#pragma unroll
      for (int mt=0; mt<MT; ++mt)
        acc[mt][nt] = __builtin_amdgcn_mfma_f32_16x16x32_bf16(af[mt], bfr, acc[mt][nt], 0, 0, 0);
    }
  }

  if constexpr (MODE == 0) {
    float* Cb = C + (long long)z*sC;
#pragma unroll
    for (int nt=0; nt<NT; ++nt) {
      const int col = n0 + wn*(BN/2) + nt*16 + lr;
      if (col < ncmax) {
        const float bv = bias ? bias[col] : 0.f;
#pragma unroll
        for (int mt=0; mt<MT; ++mt) {
#pragma unroll
          for (int r=0; r<4; ++r) {
            const int row = m0 + wm*(BM/2) + mt*16 + lq*4 + r;
            Cb[(long long)row*ldc + col] = acc[mt][nt][r] + bv;
          }
        }
      }
    }
  } else {
    const int h = z & 15;
    const float alpha = 1.f/(1.f + __expf(-araw[order*16 + h]));
    float* rb = resb + (long long)z * 65536;   // res[z][1024][64]
    __syncthreads();                           // staging LDS reuse as transpose buf
#pragma unroll
    for (int nt=0; nt<NT; ++nt) {
      const int d = wn*32 + nt*16 + lr;
#pragma unroll
      for (int mt=0; mt<MT; ++mt) {
#pragma unroll
        for (int r=0; r<4; ++r) {
          const int row = wm*(BM/2) + mt*16 + lq*4 + r;
          const float v = acc[mt][nt][r];
          const long long ri = (long long)(m0+row)*64 + d;
          rb[ri] = accum ? (rb[ri] + alpha*v) : (alpha*v);
          smem[d*136 + row] = f2bf(v);
        }
      }
    }
    __syncthreads();
    const int dd = tid>>2, cc = (tid&3)*(BM/4);
    u16* vp = vout + (long long)z*75776 + (long long)dd*1184 + m0 + cc;  // vout[z][64][1184]
    const u16* sp = smem + dd*136 + cc;
#pragma unroll
    for (int j=0; j<BM/4; j+=8) {
      uint4 uu;
      uu.x = sp[j+0] | ((u32)sp[j+1]<<16);
      uu.y = sp[j+2] | ((u32)sp[j+3]<<16);
      uu.z = sp[j+4] | ((u32)sp[j+5]<<16);
      uu.w = sp[j+6] | ((u32)sp[j+7]<<16);
      *(uint4*)(vp + j) = uu;
    }
  }
}

// ---------------------------------------------------------------------------
// Elementwise prep kernels
// ---------------------------------------------------------------------------
// fp32 [rows,1024] -> bf16 [rows,3072]; A-mode (hi|lo|hi), B-mode (hi|hi|lo)
__global__ __launch_bounds__(256) void planeize(const float* __restrict__ src, u16* __restrict__ dst,
                                                int total, int modeB){
  int idx = blockIdx.x*256 + threadIdx.x;
  if (idx >= total) return;
  int c = idx & 1023, r = idx >> 10;
  float v = src[idx];
  u16 hi = f2bf(v); u16 lo = f2bf(v - bf2f(hi));
  u16* d = dst + (long long)r*3072 + c;
  if (modeB){ d[0]=hi; d[1024]=hi; d[2048]=lo; }
  else      { d[0]=hi; d[1024]=lo; d[2048]=hi; }
}

// qkv fp32 [4096,3072] -> qS [bh,1024,192] (A-mode) and kxS rows 0..1023 (B-mode, k*0.125)
__global__ __launch_bounds__(256) void build_qk(const float* __restrict__ qkv,
                                                u16* __restrict__ qS, u16* __restrict__ kxS){
  int idx = blockIdx.x*256 + threadIdx.x;   // ((b*16+h)*1024+n)*64+d
  int d = idx & 63, n = (idx>>6) & 1023, bh = idx >> 16;
  int b = bh >> 4, h = bh & 15;
  long long src = (long long)(b*1024 + n)*3072 + h*64 + d;
  float qv = qkv[src];
  float kv = qkv[src + 1024] * 0.125f;
  u16 qhi=f2bf(qv), qlo=f2bf(qv - bf2f(qhi));
  u16 khi=f2bf(kv), klo=f2bf(kv - bf2f(khi));
  u16* q  = qS  + ((long long)bh*1024 + n)*192 + d;
  q[0]=qhi; q[64]=qlo; q[128]=qhi;
  u16* kx = kxS + ((long long)bh*1280 + n)*192 + d;
  kx[0]=khi; kx[64]=khi; kx[128]=klo;
}

// kxS rows 1024..1279: rel_k_emb planes (B-mode), zero pad rows
__global__ __launch_bounds__(256) void build_kxrel(const float* __restrict__ relk, u16* __restrict__ kxS){
  int idx = blockIdx.x*256 + threadIdx.x;   // (bh, t:256, d:64)
  int d = idx & 63, t = (idx>>6) & 255, bh = idx >> 14;
  u16 hi=0, lo=0;
  if (t < 129){ float v = relk[t*64 + d]; hi = f2bf(v); lo = f2bf(v - bf2f(hi)); }
  u16* kx = kxS + ((long long)bh*1280 + 1024 + t)*192 + d;
  kx[0]=hi; kx[64]=hi; kx[128]=lo;
}

// v part of qkv -> vA[bh][d][n] (transposed, bf16) via LDS tiles
__global__ __launch_bounds__(256) void build_vT(const float* __restrict__ qkv, u16* __restrict__ vA){
  __shared__ float tb[64][65];
  int bh = blockIdx.x >> 4, ntile = blockIdx.x & 15;
  int b = bh >> 4, h = bh & 15;
  int tid = threadIdx.x;
  int nl = tid >> 2, dc = (tid & 3)*16;
  const float* sp = qkv + (long long)(b*1024 + ntile*64 + nl)*3072 + 2048 + h*64 + dc;
#pragma unroll
  for (int j=0;j<16;j+=4){
    float4 f = *(const float4*)(sp + j);
    tb[dc+j+0][nl]=f.x; tb[dc+j+1][nl]=f.y; tb[dc+j+2][nl]=f.z; tb[dc+j+3][nl]=f.w;
  }
  __syncthreads();
  int d = tid >> 2, nc = (tid & 3)*16;
  u16* dp = vA + ((long long)bh*64 + d)*1184 + ntile*64 + nc;
#pragma unroll
  for (int j=0;j<16;j+=8){
    u16 a0=f2bf(tb[d][nc+j+0]), a1=f2bf(tb[d][nc+j+1]), a2=f2bf(tb[d][nc+j+2]), a3=f2bf(tb[d][nc+j+3]);
    u16 a4=f2bf(tb[d][nc+j+4]), a5=f2bf(tb[d][nc+j+5]), a6=f2bf(tb[d][nc+j+6]), a7=f2bf(tb[d][nc+j+7]);
    uint4 uu; uu.x=a0|((u32)a1<<16); uu.y=a2|((u32)a3<<16); uu.z=a4|((u32)a5<<16); uu.w=a6|((u32)a7<<16);
    *(uint4*)(dp + j) = uu;
  }
}

// vA ext cols: [bh][d][1024+t] = rel_v_emb[t][d] (t<129), 0 for t 129..159
__global__ __launch_bounds__(256) void build_vText(const float* __restrict__ relv, u16* __restrict__ vA){
  int idx = blockIdx.x*256 + threadIdx.x;   // (bh, d, t:160)
  int t = idx % 160; int rest = idx / 160; int d = rest & 63; int bh = rest >> 6;
  u16 hv = 0;
  if (t < 129) hv = f2bf(relv[t*64 + d]);
  vA[((long long)bh*64 + d)*1184 + 1024 + t] = hv;
}

// res [bh][n][d] fp32 -> resS [b*1024+n][3072] A-mode planes at col h*64+d
__global__ __launch_bounds__(256) void build_resS(const float* __restrict__ res, u16* __restrict__ resS){
  int idx = blockIdx.x*256 + threadIdx.x;
  int d = idx & 63, n = (idx>>6) & 1023, bh = idx >> 16;
  int b = bh >> 4, h = bh & 15;
  float v = res[idx];
  u16 hi = f2bf(v), lo = f2bf(v - bf2f(hi));
  u16* p = resS + (long long)(b*1024 + n)*3072 + h*64 + d;
  p[0]=hi; p[1024]=lo; p[2048]=hi;
}

// ---------------------------------------------------------------------------
// Per-row (one wave per row): scores row (ld 1156: cols 0..1023 = QK^T+band
// via GEMM-folded rel cols 1024..1152), exact 256th-largest threshold (radix
// bisection on sortable-uint, with exact early-exit: when count==256 the kept
// set IS the top-256 so thr = wave-min of kept), masked softmax. Writes P
// (bf16, 1184 cols: 1024 probs + 129 rel_v bucket weights + 31 zeros) IN
// PLACE over the S row. Safe: each wave reads only its own row before writing.
// ---------------------------------------------------------------------------
__global__ __launch_bounds__(256) void topk_softmax(float* S){
  __shared__ float rel[4][132];
  __shared__ float prow[4][1024];
  const int tid = threadIdx.x, wid = tid>>6, lane = tid&63;
  const int rowid = blockIdx.x*4 + wid;     // 0..32767 (one half-batch)
  const int i = rowid & 1023;
  float* Sr = S + (long long)rowid * 1156;

  rel[wid][lane]      = Sr[1024 + lane];    // rel idx 0..63
  rel[wid][64 + lane] = Sr[1088 + lane];    // rel idx 64..127
  if (lane == 0) rel[wid][128] = Sr[1152];  // rel idx 128

  float v[16];
#pragma unroll
  for (int r=0;r<4;++r){
    float4 f = *(const float4*)(Sr + r*256 + lane*4);
    v[r*4+0]=f.x; v[r*4+1]=f.y; v[r*4+2]=f.z; v[r*4+3]=f.w;
  }
  __syncthreads();   // all S reads complete before any in-place P write below
#pragma unroll
  for (int x=0;x<16;++x){
    const int j = (x>>2)*256 + lane*4 + (x&3);
    int dl = i - j; dl = dl > 64 ? 64 : (dl < -64 ? -64 : dl);
    v[x] += rel[wid][dl + 64];
  }
  u32 u[16];
#pragma unroll
  for (int x=0;x<16;++x){
    u32 bb = __float_as_uint(v[x]);
    u[x] = bb ^ ((u32)((int)bb >> 31) | 0x80000000u);
  }
  u32 thr = 0;
#pragma unroll 1
  for (int bit=31; bit>=0; --bit){
    const u32 cand = thr | (1u<<bit);
    int c = 0;
#pragma unroll
    for (int x=0;x<16;++x) c += __popcll(__ballot(u[x] >= cand));
    if (c == 256){
      // kept set is exactly the top-256: threshold = min of kept (exact)
      u32 mn = 0xFFFFFFFFu;
#pragma unroll
      for (int x=0;x<16;++x) if (u[x] >= cand && u[x] < mn) mn = u[x];
      for (int o=32;o;o>>=1){ u32 t = __shfl_xor(mn, o); mn = t < mn ? t : mn; }
      thr = mn;
      break;
    }
    if (c > 256) thr = cand;
  }
  float m = -3.0e38f;
#pragma unroll
  for (int x=0;x<16;++x) m = fmaxf(m, v[x]);
  for (int o=32;o;o>>=1) m = fmaxf(m, __shfl_xor(m, o));
  float e[16]; float Z = 0.f;
#pragma unroll
  for (int x=0;x<16;++x){
    e[x] = (u[x] >= thr) ? __expf(v[x]-m) : 0.f;
    Z += e[x];
  }
  for (int o=32;o;o>>=1) Z += __shfl_xor(Z, o);
  const float rz = 1.f / Z;

  u16* Pr = (u16*)Sr;                       // in-place: P row stride 2312 u16
#pragma unroll
  for (int r=0;r<4;++r){
    float p0=e[r*4+0]*rz, p1=e[r*4+1]*rz, p2=e[r*4+2]*rz, p3=e[r*4+3]*rz;
    prow[wid][r*256+lane*4+0]=p0; prow[wid][r*256+lane*4+1]=p1;
    prow[wid][r*256+lane*4+2]=p2; prow[wid][r*256+lane*4+3]=p3;
    uint2 uu; uu.x = f2bf(p0) | ((u32)f2bf(p1)<<16); uu.y = f2bf(p2) | ((u32)f2bf(p3)<<16);
    *(uint2*)(Pr + r*256 + lane*4) = uu;
  }
  float s0 = 0.f, s1 = 0.f;
#pragma unroll
  for (int x=0;x<16;++x){
    const int j = (x>>2)*256 + lane*4 + (x&3);
    const float p = e[x]*rz;
    if (j >= i+64) s0 += p;    // dist bucket t=0   (j >= i+64)
    if (j <= i-64) s1 += p;    // dist bucket t=128 (j <= i-64)
  }
  for (int o=32;o;o>>=1){ s0 += __shfl_xor(s0,o); s1 += __shfl_xor(s1,o); }
  {
    const int t = lane + 1;                 // 1..64
    const int j = i + 64 - t;
    const float wv = (j>=0 && j<1024) ? prow[wid][j] : 0.f;
    Pr[1024 + t] = f2bf(wv);
    if (lane < 63){
      const int t2 = lane + 65;             // 65..127
      const int j2 = i + 64 - t2;
      const float wv2 = (j2>=0 && j2<1024) ? prow[wid][j2] : 0.f;
      Pr[1024 + t2] = f2bf(wv2);
    }
    if (lane == 0){ Pr[1024] = f2bf(s0); Pr[1152] = f2bf(s1); }
    if (lane >= 33) Pr[1120 + lane] = 0;    // zero cols 1153..1183
  }
}

// ---------------------------------------------------------------------------
extern "C" void kernel_launch(void* const* d_in, const int* in_sizes, int n_in,
                              void* d_out, int out_size, void* d_ws, size_t ws_size,
                              hipStream_t stream) {
  const float* x    = (const float*)d_in[0];
  const float* Wqkv = (const float*)d_in[1];
  const float* bqkv = (const float*)d_in[2];
  const float* Wout = (const float*)d_in[3];
  const float* bout = (const float*)d_in[4];
  const float* relk = (const float*)d_in[5];
  const float* relv = (const float*)d_in[6];
  const float* araw = (const float*)d_in[7];
  float* out = (float*)d_out;

  char* w = (char*)d_ws;
  size_t off = 0;
  auto take = [&](size_t bytes)->char*{ char* p = w + off; off += (bytes + 255) & ~(size_t)255; return p; };

  // regionS (151.5 MB): phase1 {xS|wqS|qkv32} -> per-half {S/P overlay} -> {resS|woS}
  char* regionS = take(151519232);          // 32*1024 rows * 1156 fp32
  u16*   xS    = (u16*)  (regionS);
  u16*   wqS   = (u16*)  (regionS + 25165824);
  float* qkv32 = (float*)(regionS + 25165824 + 18874368);
  float* Sh    = (float*)(regionS);
  u16*   Ph    = (u16*)  (regionS);         // in-place, row stride 2312 u16
  u16*   resS  = (u16*)  (regionS);
  u16*   woS   = (u16*)  (regionS + 25165824);
  u16*   qS    = (u16*)take(25165824);      // [64][1024][192]
  u16*   kxS   = (u16*)take(31457280);      // [64][1280][192]
  u16*   vA    = (u16*)take(9699328);       // [64][64][1184]
  u16*   vB    = (u16*)take(9699328);
  float* res   = (float*)take(16777216);    // [64][1024][64]
  (void)ws_size; (void)in_sizes; (void)n_in; (void)out_size;
  // total ~233 MiB

  // phase 1: QKV projection. qk at split-fp32 (K=3072 planes); v consumed as
  // bf16 downstream, so hi*hi only (K=1024) — same buffers, shorter K.
  planeize<<<16384,256,0,stream>>>(x,    xS,  4194304, 0);
  planeize<<<12288,256,0,stream>>>(Wqkv, wqS, 3145728, 1);
  gemm_bt<128,128,0><<<dim3(16,32,1),256,0,stream>>>(xS, wqS, qkv32, bqkv,
      3072, 3072, 3072, 3072, 2048, 0, 0, 0, nullptr, nullptr, nullptr, 0, 0);
  gemm_bt<128,128,0><<<dim3(8,32,1),256,0,stream>>>(xS, wqS + (long long)2048*3072,
      qkv32 + 2048, bqkv + 2048,
      1024, 3072, 3072, 3072, 1024, 0, 0, 0, nullptr, nullptr, nullptr, 0, 0);
  build_qk   <<<16384,256,0,stream>>>(qkv32, qS, kxS);
  build_kxrel<<<4096, 256,0,stream>>>(relk, kxS);
  build_vT   <<<1024, 256,0,stream>>>(qkv32, vA);
  build_vText<<<2560, 256,0,stream>>>(relv, vA);

  // phases 2+3 per 32-head half: scores -> topk/softmax (P in place) -> 3x AV
  for (int half = 0; half < 2; ++half) {
    const long long zo = (long long)half * 32;
    gemm_bt<128,128,0><<<dim3(10,8,32),256,0,stream>>>(
        qS + zo*196608, kxS + zo*245760, Sh, nullptr,
        192, 192, 192, 1156, 1153, 196608LL, 245760LL, 1183744LL,
        nullptr, nullptr, nullptr, 0, 0);
    topk_softmax<<<8192,256,0,stream>>>(Sh);
    gemm_bt<64,64,1><<<dim3(1,16,32),256,0,stream>>>(Ph, vA + zo*75776, nullptr, nullptr,
        1184, 2312, 1184, 0, 0, 2367488LL, 75776LL, 0LL,
        vB + zo*75776, res + zo*65536, araw, 0, 0);
    gemm_bt<64,64,1><<<dim3(1,16,32),256,0,stream>>>(Ph, vB + zo*75776, nullptr, nullptr,
        1024, 2312, 1184, 0, 0, 2367488LL, 75776LL, 0LL,
        vA + zo*75776, res + zo*65536, araw, 1, 1);
    gemm_bt<64,64,1><<<dim3(1,16,32),256,0,stream>>>(Ph, vA + zo*75776, nullptr, nullptr,
        1024, 2312, 1184, 0, 0, 2367488LL, 75776LL, 0LL,
        vB + zo*75776, res + zo*65536, araw, 2, 1);
  }

  // output projection (fp32 via split planes), BM=64 for 512-block occupancy
  build_resS<<<16384,256,0,stream>>>(res, resS);
  planeize  <<<4096, 256,0,stream>>>(Wout, woS, 1048576, 1);
  gemm_bt<64,128,0><<<dim3(8,64,1),256,0,stream>>>(resS, woS, out, bout,
      3072, 3072, 3072, 1024, 1024, 0, 0, 0, nullptr, nullptr, nullptr, 0, 0);
}